// Round 6
// baseline (131.378 us; speedup 1.0000x reference)
//
#include <hip/hip_runtime.h>
#include <stdint.h>

#define B 8
#define N 1000
#define C 91
#define NC 90            // classes minus background
#define D 1024
#define KMAX 2048        // NMS_TOPK
#define PAD 4096         // key slots/image: 4*N=4000 used (<=4 classes/row can have softmax>0.2), rest zero
#define DETS 36
#define SCORE_THRESH 0.2f
#define NMS_THRESH 0.5f
#define MIN_SIZE 0.01f
#define XFORM_CLIP 4.135166556742356f   // log(1000/16)

// ---- shared decode so all kernels produce bit-identical boxes ----
__device__ __forceinline__ void decode_clip(const float* __restrict__ rg,
                                            float wdt, float hgt, float cx, float cy,
                                            float W, float H,
                                            float& x1, float& y1, float& x2, float& y2) {
    float dx = rg[0] / 10.0f;
    float dy = rg[1] / 10.0f;
    float dw = fminf(rg[2] / 5.0f, XFORM_CLIP);
    float dh = fminf(rg[3] / 5.0f, XFORM_CLIP);
    float pcx = dx * wdt + cx;
    float pcy = dy * hgt + cy;
    float pw  = expf(dw) * wdt;
    float ph  = expf(dh) * hgt;
    x1 = fminf(fmaxf(pcx - 0.5f * pw, 0.0f), W);
    y1 = fminf(fmaxf(pcy - 0.5f * ph, 0.0f), H);
    x2 = fminf(fmaxf(pcx + 0.5f * pw, 0.0f), W);
    y2 = fminf(fmaxf(pcy + 0.5f * ph, 0.0f), H);
}

// ---- kernel 1: wave-per-row class-parallel softmax + decode + filter.
// Fixed slots keys[n*4+p] via ballot compaction; no atomics, no memset.
// (unchanged from R5)
__global__ __launch_bounds__(256) void k_score(const float* __restrict__ logits,
                        const float* __restrict__ reg,
                        const float* __restrict__ props,
                        const int* __restrict__ img_hw,
                        unsigned long long* __restrict__ keys) {
    int b = blockIdx.x / 250;            // 250 blocks per image, 4 rows per block
    int local = blockIdx.x % 250;
    int wib = threadIdx.x >> 6, lane = threadIdx.x & 63;
    int n = local * 4 + wib;
    int r = b * N + n;

    __shared__ unsigned long long slot[4][4];
    if (threadIdx.x < 16) slot[threadIdx.x >> 2][threadIdx.x & 3] = 0ULL;
    __syncthreads();

    const float* lg = logits + (size_t)r * C;
    float v0 = lg[lane];                                   // classes 0..63
    float v1 = (lane < C - 64) ? lg[64 + lane] : -3.4e38f; // classes 64..90
    float m = fmaxf(v0, v1);
    #pragma unroll
    for (int off = 32; off; off >>= 1) m = fmaxf(m, __shfl_xor(m, off, 64));
    float e0 = expf(v0 - m);
    float e1 = (lane < C - 64) ? expf(v1 - m) : 0.0f;
    float s = e0 + e1;
    #pragma unroll
    for (int off = 32; off; off >>= 1) s += __shfl_xor(s, off, 64);

    float p0 = props[r * 4 + 0], p1 = props[r * 4 + 1];
    float p2 = props[r * 4 + 2], p3 = props[r * 4 + 3];
    float wdt = p2 - p0, hgt = p3 - p1;
    float cx = p0 + 0.5f * wdt, cy = p1 + 0.5f * hgt;
    float H = (float)img_hw[b * 2 + 0];
    float W = (float)img_hw[b * 2 + 1];

    unsigned long long keyv[2] = {0ULL, 0ULL};
    #pragma unroll
    for (int t2 = 0; t2 < 2; ++t2) {
        int c = lane + t2 * 64;
        float e = t2 ? e1 : e0;
        if (c >= 1 && c < C) {
            float sc = e / s;
            if (sc > SCORE_THRESH) {
                const float* rg = reg + (size_t)r * (C * 4) + (size_t)c * 4;
                float x1, y1, x2, y2;
                decode_clip(rg, wdt, hgt, cx, cy, W, H, x1, y1, x2, y2);
                if ((x2 - x1) >= MIN_SIZE && (y2 - y1) >= MIN_SIZE) {
                    unsigned int idx = (unsigned int)(n * NC + (c - 1));
                    keyv[t2] = ((unsigned long long)__float_as_uint(sc) << 32) |
                               (unsigned long long)(0xFFFFFFFFu - idx);
                }
            }
        }
    }
    unsigned long long m0 = __ballot(keyv[0] != 0ULL);
    unsigned long long m1 = __ballot(keyv[1] != 0ULL);
    unsigned long long lower = (1ULL << lane) - 1ULL;
    if (keyv[0]) slot[wib][__popcll(m0 & lower)] = keyv[0];
    if (keyv[1]) slot[wib][__popcll(m0) + __popcll(m1 & lower)] = keyv[1];
    __syncthreads();
    if (threadIdx.x < 16) {
        int ww = threadIdx.x >> 2, p = threadIdx.x & 3;
        keys[(size_t)b * PAD + (size_t)(local * 4 + ww) * 4 + p] = slot[ww][p];
    }
}

// ---- kernel 2: rank-and-scatter, 4-rows-per-lane. sorted pos == #{keys > mine}.
// 16 blocks/image x 512 threads. Block ranks 256 rows; each of its 8 waves
// scans a 512-key slice against 4 register-held row keys (1 broadcast LDS
// read feeds 256 compares -> LDS issue drops below the VALU cost). Partials
// combined in LDS; winning rows decode + scatter to their rank slot.
// Row 4*N is always zero-keyed: its rank == V_valid -> writes Kvals for free.
__global__ __launch_bounds__(512) void k_rank(int* __restrict__ Kvals,
                                              const unsigned long long* __restrict__ keys,
                                              const float* __restrict__ reg,
                                              const float* __restrict__ props,
                                              const int* __restrict__ img_hw,
                                              float* __restrict__ bx1, float* __restrict__ by1,
                                              float* __restrict__ bx2, float* __restrict__ by2,
                                              int* __restrict__ propn) {
    __shared__ unsigned long long sk[PAD];   // 32 KB
    __shared__ int partial[8][256];          // 8 KB
    int b = blockIdx.y;
    const unsigned long long* kb = keys + (size_t)b * PAD;
    for (int t = threadIdx.x; t < PAD; t += 512)
        sk[t] = (t < 4 * N) ? kb[t] : 0ULL;  // zero-pad: never outranks a valid key
    __syncthreads();

    int w = threadIdx.x >> 6;                // wave 0..7 (key-slice, wave-uniform)
    int lane = threadIdx.x & 63;
    int rbase = blockIdx.x * 256;            // block's 256 rows (absolute in image)
    unsigned long long my0 = sk[rbase + lane];
    unsigned long long my1 = sk[rbase + lane + 64];
    unsigned long long my2 = sk[rbase + lane + 128];
    unsigned long long my3 = sk[rbase + lane + 192];
    int c0 = 0, c1 = 0, c2 = 0, c3 = 0;
    int base = w * 512;
    #pragma unroll 8
    for (int it = 0; it < 512; ++it) {
        unsigned long long k = sk[base + it];    // wave-uniform -> broadcast
        c0 += (k > my0) ? 1 : 0;
        c1 += (k > my1) ? 1 : 0;
        c2 += (k > my2) ? 1 : 0;
        c3 += (k > my3) ? 1 : 0;
    }
    partial[w][lane]       = c0;
    partial[w][lane + 64]  = c1;
    partial[w][lane + 128] = c2;
    partial[w][lane + 192] = c3;
    __syncthreads();

    if (threadIdx.x < 256) {
        int rl = threadIdx.x;
        int rank = 0;
        #pragma unroll
        for (int q = 0; q < 8; ++q) rank += partial[q][rl];
        int row = rbase + rl;
        unsigned long long my = sk[row];
        if (row == 4 * N) Kvals[b] = (rank < KMAX) ? rank : KMAX;  // rank of zero key == V_valid
        if (my != 0ULL && rank < KMAX) {
            unsigned int idx = 0xFFFFFFFFu - (unsigned int)(my & 0xFFFFFFFFull);
            int n = (int)(idx / NC);
            int c = (int)(idx % NC) + 1;
            int r = b * N + n;
            float p0 = props[r * 4 + 0], p1 = props[r * 4 + 1];
            float p2 = props[r * 4 + 2], p3 = props[r * 4 + 3];
            float wdt = p2 - p0, hgt = p3 - p1;
            float cx = p0 + 0.5f * wdt, cy = p1 + 0.5f * hgt;
            float H = (float)img_hw[b * 2 + 0];
            float W = (float)img_hw[b * 2 + 1];
            const float* rg = reg + (size_t)r * (C * 4) + (size_t)c * 4;
            float x1, y1, x2, y2;
            decode_clip(rg, wdt, hgt, cx, cy, W, H, x1, y1, x2, y2);
            size_t o = (size_t)b * KMAX + rank;
            bx1[o] = x1; by1[o] = y1; bx2[o] = x2; by2[o] = y2;
            propn[o] = n;
        }
    }
}

// ---- kernel 3: fused greedy NMS + feature gather, one block per image.
// Wave 0 runs the R5 NMS (suppression flows only from kept (<=36): per
// 64-chunk, check vs kept list, then pop lowest live rank via ffsll+shfl;
// early exit at 36). Then all 256 threads gather the 36 feature rows.
__global__ __launch_bounds__(256) void k_nmsg(const int* __restrict__ Kvals,
                                              const float* __restrict__ bx1, const float* __restrict__ by1,
                                              const float* __restrict__ bx2, const float* __restrict__ by2,
                                              const int* __restrict__ propn,
                                              const float* __restrict__ feats,
                                              float* __restrict__ out) {
    __shared__ float kx1[DETS], ky1[DETS], kx2[DETS], ky2[DETS];
    __shared__ int kpn[DETS];
    __shared__ int skept;
    int b = blockIdx.x, lane = threadIdx.x;

    if (threadIdx.x < 64) {
        int K = Kvals[b];
        size_t ofs = (size_t)b * KMAX;
        int kept = 0;
        for (int cs = 0; cs < K && kept < DETS; cs += 64) {
            int j = cs + lane;
            bool inr = (j < K);
            int jj = inr ? j : 0;
            float x1 = bx1[ofs + jj], y1 = by1[ofs + jj];
            float x2 = bx2[ofs + jj], y2 = by2[ofs + jj];
            int pn = propn[ofs + jj];
            float area = (x2 - x1) * (y2 - y1);

            bool supp = !inr;
            for (int k = 0; k < kept; ++k) {
                float c1 = kx1[k], c2 = ky1[k], c3 = kx2[k], c4 = ky2[k];
                float carea = (c3 - c1) * (c4 - c2);
                float ix1 = fmaxf(c1, x1), iy1 = fmaxf(c2, y1);
                float ix2 = fminf(c3, x2), iy2 = fminf(c4, y2);
                float iw = fmaxf(ix2 - ix1, 0.0f), ih = fmaxf(iy2 - iy1, 0.0f);
                float inter = iw * ih;
                float uni = carea + area - inter;
                float iou = (uni > 0.0f) ? (inter / uni) : 0.0f;
                supp = supp || (iou > NMS_THRESH);
            }
            unsigned long long live = __ballot(!supp);
            while (live != 0ULL && kept < DETS) {
                int i = __ffsll((unsigned long long)live) - 1;
                float c1 = __shfl(x1, i, 64), c2 = __shfl(y1, i, 64);
                float c3 = __shfl(x2, i, 64), c4 = __shfl(y2, i, 64);
                int   cp = __shfl(pn, i, 64);
                if (lane == 0) { kx1[kept] = c1; ky1[kept] = c2; kx2[kept] = c3; ky2[kept] = c4; kpn[kept] = cp; }
                kept++;
                float carea = (c3 - c1) * (c4 - c2);
                float ix1 = fmaxf(c1, x1), iy1 = fmaxf(c2, y1);
                float ix2 = fminf(c3, x2), iy2 = fminf(c4, y2);
                float iw = fmaxf(ix2 - ix1, 0.0f), ih = fmaxf(iy2 - iy1, 0.0f);
                float inter = iw * ih;
                float uni = carea + area - inter;
                float iou = (uni > 0.0f) ? (inter / uni) : 0.0f;
                live &= ~__ballot(iou > NMS_THRESH);     // clears bit i too (self IoU=1)
            }
        }
        if (lane == 0) skept = kept;
    }
    __syncthreads();

    int kept = skept;
    int t = threadIdx.x;                 // float4 index 0..255 within a row
    const float4* f4 = (const float4*)feats;
    float4* o4 = (float4*)out;
    for (int s = 0; s < DETS; ++s) {
        float4 v = make_float4(0.f, 0.f, 0.f, 0.f);
        if (s < kept) v = f4[((size_t)b * N + kpn[s]) * (D / 4) + t];
        o4[((size_t)b * DETS + s) * (D / 4) + t] = v;
    }
}

extern "C" void kernel_launch(void* const* d_in, const int* in_sizes, int n_in,
                              void* d_out, int out_size, void* d_ws, size_t ws_size,
                              hipStream_t stream) {
    const float* logits = (const float*)d_in[0];   // [B,N,C]
    const float* reg    = (const float*)d_in[1];   // [B,N,C*4]
    const float* props  = (const float*)d_in[2];   // [B,N,4]
    const float* feats  = (const float*)d_in[3];   // [B,N,D]
    const int*   img    = (const int*)d_in[4];     // [B,2]
    float* out = (float*)d_out;                    // [B,DETS,D]

    char* ws = (char*)d_ws;
    int* Kvals    = (int*)(ws + 0);                        // 8 ints (written unconditionally by k_rank)
    unsigned long long* keys = (unsigned long long*)(ws + 4096);      // 8*4096 u64 = 256KB (fully written by k_score)
    float* bx1 = (float*)(ws + 270336);                    // each 8*2048*4 = 64KB (ranks >= K guarded)
    float* by1 = (float*)(ws + 335872);
    float* bx2 = (float*)(ws + 401408);
    float* by2 = (float*)(ws + 466944);
    int*   propn = (int*)(ws + 532480);                    // 64KB

    k_score<<<dim3(B * 250), dim3(256), 0, stream>>>(logits, reg, props, img, keys);
    k_rank<<<dim3(16, B), dim3(512), 0, stream>>>(Kvals, keys,
        reg, props, img, bx1, by1, bx2, by2, propn);
    k_nmsg<<<dim3(B), dim3(256), 0, stream>>>(Kvals, bx1, by1, bx2, by2, propn, feats, out);
}